// Round 13
// baseline (569.539 us; speedup 1.0000x reference)
//
#include <hip/hip_runtime.h>
#include <math.h>

constexpr int CN = 4096, CHH = 8, CD = 64, CM = 128;
constexpr int V1P_OFF = 16 * 4096 * 8 * 64;             // 33554432 floats
constexpr int V2P_OFF = V1P_OFF + 16 * 4096 * 8 * 128;  // 100663296 floats
constexpr float KSCALE = 0.35355339059327373f;          // 64^-0.25 (tau=1)
constexpr float KRATIO = 0.08838834764831843f;          // 1/sqrt(128)
constexpr float KEPS   = 1e-6f;

typedef __attribute__((ext_vector_type(8))) short bf16x8;
typedef __attribute__((ext_vector_type(4))) float f32x4;

__device__ __forceinline__ float dot4(float4 a, float4 b) {
  return fmaf(a.x, b.x, fmaf(a.y, b.y, fmaf(a.z, b.z, a.w * b.w)));
}
__device__ __forceinline__ float4 scl4(float4 a, float s) {
  return make_float4(a.x * s, a.y * s, a.z * s, a.w * s);
}
__device__ __forceinline__ short bhi(float f) {
  return (short)(__float_as_uint(f) >> 16);          // truncate to bf16
}
__device__ __forceinline__ float bf2f(short s) {
  return __uint_as_float(((unsigned)(unsigned short)s) << 16);
}
__device__ __forceinline__ void split8(float4 u, float4 v, bf16x8& hi, bf16x8& lo) {
  float a[8] = {u.x, u.y, u.z, u.w, v.x, v.y, v.z, v.w};
#pragma unroll
  for (int e = 0; e < 8; e++) {
    short h = bhi(a[e]);
    hi[e] = h;
    lo[e] = bhi(a[e] - bf2f(h));
  }
}
__device__ __forceinline__ void split8a(const float* a, bf16x8& hi, bf16x8& lo) {
#pragma unroll
  for (int e = 0; e < 8; e++) {
    short h = bhi(a[e]);
    hi[e] = h;
    lo[e] = bhi(a[e] - bf2f(h));
  }
}

#define MFMA_B16(A, B, C) __builtin_amdgcn_mfma_f32_16x16x32_bf16(A, B, C, 0, 0, 0)

// full-precision proj fragments (hi+lo), ~128 VGPR
#define LOAD_BFRAGS(proj, lm, ko)                                   \
  bf16x8 Bh0[8], Bl0[8], Bh1[8], Bl1[8];                            \
  _Pragma("unroll")                                                 \
  for (int t = 0; t < 8; t++) {                                     \
    const float* pb = (proj) + (t * 16 + (lm)) * 64 + (ko);         \
    float4 p0 = *(const float4*)(pb);                               \
    float4 p1 = *(const float4*)(pb + 4);                           \
    float4 p2 = *(const float4*)(pb + 32);                          \
    float4 p3 = *(const float4*)(pb + 36);                          \
    split8(p0, p1, Bh0[t], Bl0[t]);                                 \
    split8(p2, p3, Bh1[t], Bl1[t]);                                 \
  }

// 6-term hi/lo MFMA chain for one j-tile t
#define PROJ_MFMA(acc, t)                                           \
  do {                                                              \
    acc = MFMA_B16(Ah0, Bh0[t], acc);                               \
    acc = MFMA_B16(Ah1, Bh1[t], acc);                               \
    acc = MFMA_B16(Al0, Bh0[t], acc);                               \
    acc = MFMA_B16(Al1, Bh1[t], acc);                               \
    acc = MFMA_B16(Ah0, Bl0[t], acc);                               \
    acc = MFMA_B16(Ah1, Bl1[t], acc);                               \
  } while (0)

// ---- kp_stat: per-(b,h)-chunk max of dd for v2. FULL 6-term precision.
//      (r12 lesson: hi-only max fails — the +eps term breaks the
//      exp(-delta) scale-cancellation in out1/out2, and eps DOMINATES most
//      v2p entries since typical dd-diag-mx ~ -18 -> exp ~ 1e-8 << 1e-6.)
__global__ __launch_bounds__(256) void kp_stat(
    const float* __restrict__ inp, const float* __restrict__ proj,
    float* __restrict__ outmax) {
  const int l = threadIdx.x & 63, w = threadIdx.x >> 6;
  const int lm = l & 15, lk = l >> 4, ko = lk * 8;
  LOAD_BFRAGS(proj, lm, ko);
  const int bh = blockIdx.x >> 3, ch = blockIdx.x & 7;
  const int b = bh >> 3, h = bh & 7;
  float bmax = -1e30f;
  for (int s = 0; s < 8; s++) {
    const int nb = ch * 512 + w * 128 + s * 16;
    const size_t rA = (size_t)((b * CN + nb + lm) * CHH + h);
    const float* pa = inp + rA * 64 + ko;
    float4 a0 = scl4(*(const float4*)(pa), KSCALE);
    float4 a1 = scl4(*(const float4*)(pa + 4), KSCALE);
    float4 a2 = scl4(*(const float4*)(pa + 32), KSCALE);
    float4 a3 = scl4(*(const float4*)(pa + 36), KSCALE);
    bf16x8 Ah0, Al0, Ah1, Al1;
    split8(a0, a1, Ah0, Al0);
    split8(a2, a3, Ah1, Al1);
    float rm[4] = {-1e30f, -1e30f, -1e30f, -1e30f};
#pragma unroll
    for (int t = 0; t < 8; t++) {
      f32x4 acc = {0.f, 0.f, 0.f, 0.f};
      PROJ_MFMA(acc, t);
#pragma unroll
      for (int r = 0; r < 4; r++) rm[r] = fmaxf(rm[r], acc[r]);
    }
    bmax = fmaxf(fmaxf(bmax, fmaxf(rm[0], rm[1])), fmaxf(rm[2], rm[3]));
  }
  float v = bmax;
#pragma unroll
  for (int d = 1; d < 64; d <<= 1) v = fmaxf(v, __shfl_xor(v, d));
  __shared__ float wred[4];
  if (l == 0) wred[w] = v;
  __syncthreads();
  if (threadIdx.x == 0)
    outmax[blockIdx.x] = fmaxf(fmaxf(wred[0], wred[1]), fmaxf(wred[2], wred[3]));
}

// ---- k2b: reduce 8 chunk maxes -> per-bh max
__global__ void k2b_max(const float* __restrict__ partmax, float* __restrict__ wmax) {
  const int bh = threadIdx.x;  // 128 threads
  float m = -1e30f;
#pragma unroll
  for (int c = 0; c < 8; c++) m = fmaxf(m, partmax[bh * 8 + c]);
  wmax[bh] = m;
}

// ---- kemit3: FUSED v2p emit + partial v2x GEMM (r12 structure, verified
//      logic). Per 64-row tile: exp phase writes v2p (global) + LDS
//      [64][129]; barrier; GEMM phase A-frags from LDS, x from global,
//      acc[2 jt][4 dt] per wave. Saves the 268MB v2p re-read.
__global__ __launch_bounds__(256) void kemit3(
    const float* __restrict__ nv2, const float* __restrict__ x,
    const float* __restrict__ proj, const float* __restrict__ mxin,
    float* __restrict__ v2p, float* __restrict__ part,
    float* __restrict__ vsumpart) {
  __shared__ float tile[64 * 129];   // exp'd v2p tile, pad 129 (2-way max)
  __shared__ float vred[4][128];
  const int l = threadIdx.x & 63, w = threadIdx.x >> 6;
  const int lm = l & 15, lk = l >> 4, ko = lk * 8;
  LOAD_BFRAGS(proj, lm, ko);
  const int bh = blockIdx.x >> 3, ch = blockIdx.x & 7;
  const int b = bh >> 3, h = bh & 7;
  const float whm = mxin[bh];
  const int jt0 = w * 2;             // this wave's GEMM j-tiles
  f32x4 acc[2][4];
#pragma unroll
  for (int jj = 0; jj < 2; jj++)
#pragma unroll
    for (int dt = 0; dt < 4; dt++) acc[jj][dt] = (f32x4){0.f, 0.f, 0.f, 0.f};
  float vs[8] = {0.f, 0.f, 0.f, 0.f, 0.f, 0.f, 0.f, 0.f};
  for (int s = 0; s < 8; s++) {
    // ---- exp phase: this wave's 16 rows of the 64-row tile ----
    const int nb = ch * 512 + s * 64 + w * 16;
    const size_t rA = (size_t)((b * CN + nb + lm) * CHH + h);
    const float* pa = nv2 + rA * 64 + ko;
    float4 a0 = scl4(*(const float4*)(pa), KSCALE);
    float4 a1 = scl4(*(const float4*)(pa + 4), KSCALE);
    float4 a2 = scl4(*(const float4*)(pa + 32), KSCALE);
    float4 a3 = scl4(*(const float4*)(pa + 36), KSCALE);
    bf16x8 Ah0, Al0, Ah1, Al1;
    split8(a0, a1, Ah0, Al0);
    split8(a2, a3, Ah1, Al1);
    float dp = dot4(a0, a0) + dot4(a1, a1) + dot4(a2, a2) + dot4(a3, a3);
    dp += __shfl_xor(dp, 16);
    dp += __shfl_xor(dp, 32);
    float c[4];
    size_t obase[4];
#pragma unroll
    for (int r = 0; r < 4; r++) {
      const float dg = __shfl(dp, lk * 4 + r);
      const size_t rr = (size_t)((b * CN + nb + lk * 4 + r) * CHH + h);
      c[r] = -(0.5f * dg + whm);
      obase[r] = rr * CM + lm;
    }
#pragma unroll
    for (int t = 0; t < 8; t++) {
      f32x4 a = {0.f, 0.f, 0.f, 0.f};
      PROJ_MFMA(a, t);
#pragma unroll
      for (int r = 0; r < 4; r++) {
        const float val = KRATIO * (__expf(a[r] + c[r]) + KEPS);
        v2p[obase[r] + t * 16] = val;
        tile[(w * 16 + lk * 4 + r) * 129 + t * 16 + lm] = val;
        vs[t] += val;
      }
    }
    __syncthreads();
    // ---- GEMM phase: K = 64 local rows, 2 K-steps of 32 ----
#pragma unroll
    for (int ks = 0; ks < 2; ks++) {
      bf16x8 Ah[2], Al[2];
#pragma unroll
      for (int jj = 0; jj < 2; jj++) {
        float af[8];
#pragma unroll
        for (int e = 0; e < 8; e++)
          af[e] = tile[(ks * 32 + lk * 8 + e) * 129 + (jt0 + jj) * 16 + lm];
        split8a(af, Ah[jj], Al[jj]);
      }
      const int n0 = ch * 512 + s * 64 + ks * 32 + lk * 8;
#pragma unroll
      for (int dt = 0; dt < 4; dt++) {
        float bfv[8];
#pragma unroll
        for (int e = 0; e < 8; e++)
          bfv[e] = x[(size_t)((b * CN + n0 + e) * CHH + h) * CD + dt * 16 + lm];
        bf16x8 Bh, Bl;
        split8a(bfv, Bh, Bl);
#pragma unroll
        for (int jj = 0; jj < 2; jj++) {
          acc[jj][dt] = MFMA_B16(Ah[jj], Bh, acc[jj][dt]);
          acc[jj][dt] = MFMA_B16(Al[jj], Bh, acc[jj][dt]);
          acc[jj][dt] = MFMA_B16(Ah[jj], Bl, acc[jj][dt]);
        }
      }
    }
    __syncthreads();
  }
  const size_t pbase = (size_t)blockIdx.x * 8192;    // = (bh*8+ch)*8192
#pragma unroll
  for (int jj = 0; jj < 2; jj++)
#pragma unroll
    for (int dt = 0; dt < 4; dt++)
#pragma unroll
      for (int r = 0; r < 4; r++)
        part[pbase + ((size_t)(jt0 + jj) * 16 + lk * 4 + r) * 64 + dt * 16 + lm] = acc[jj][dt][r];
  // vsum: reduce lk groups, then cross-wave via LDS
#pragma unroll
  for (int t = 0; t < 8; t++) {
    float v = vs[t];
    v += __shfl_xor(v, 16);
    v += __shfl_xor(v, 32);
    if (lk == 0) vred[w][t * 16 + lm] = v;
  }
  __syncthreads();
  if (threadIdx.x < 128) {
    const int j = threadIdx.x;
    vsumpart[(size_t)blockIdx.x * 128 + j] =
        vred[0][j] + vred[1][j] + vred[2][j] + vred[3][j];
  }
}

// ---- kv1e: fused v1p pass (r11, verified)
__global__ __launch_bounds__(256) void kv1e(
    const float* __restrict__ inp, const float* __restrict__ proj,
    float* __restrict__ outp) {
  const int l = threadIdx.x & 63, w = threadIdx.x >> 6;
  const int lm = l & 15, lk = l >> 4, ko = lk * 8;
  LOAD_BFRAGS(proj, lm, ko);
  const int bh = blockIdx.x >> 3, ch = blockIdx.x & 7;
  const int b = bh >> 3, h = bh & 7;
  for (int s = 0; s < 8; s++) {
    const int nb = ch * 512 + w * 128 + s * 16;
    const size_t rA = (size_t)((b * CN + nb + lm) * CHH + h);
    const float* pa = inp + rA * 64 + ko;
    float4 a0 = scl4(*(const float4*)(pa), KSCALE);
    float4 a1 = scl4(*(const float4*)(pa + 4), KSCALE);
    float4 a2 = scl4(*(const float4*)(pa + 32), KSCALE);
    float4 a3 = scl4(*(const float4*)(pa + 36), KSCALE);
    bf16x8 Ah0, Al0, Ah1, Al1;
    split8(a0, a1, Ah0, Al0);
    split8(a2, a3, Ah1, Al1);
    float dp = dot4(a0, a0) + dot4(a1, a1) + dot4(a2, a2) + dot4(a3, a3);
    dp += __shfl_xor(dp, 16);
    dp += __shfl_xor(dp, 32);
    f32x4 acc8[8];
#pragma unroll
    for (int t = 0; t < 8; t++) {
      f32x4 acc = {0.f, 0.f, 0.f, 0.f};
      PROJ_MFMA(acc, t);
      acc8[t] = acc;
    }
    float rm[4];
#pragma unroll
    for (int r = 0; r < 4; r++) {
      float m = acc8[0][r];
#pragma unroll
      for (int t = 1; t < 8; t++) m = fmaxf(m, acc8[t][r]);
      m = fmaxf(m, __shfl_xor(m, 1));
      m = fmaxf(m, __shfl_xor(m, 2));
      m = fmaxf(m, __shfl_xor(m, 4));
      m = fmaxf(m, __shfl_xor(m, 8));
      rm[r] = m;
    }
    float c[4];
    size_t obase[4];
#pragma unroll
    for (int r = 0; r < 4; r++) {
      const float dg = __shfl(dp, lk * 4 + r);
      const size_t rr = (size_t)((b * CN + nb + lk * 4 + r) * CHH + h);
      c[r] = -(0.5f * dg + rm[r]);
      obase[r] = rr * CM + lm;
    }
#pragma unroll
    for (int t = 0; t < 8; t++) {
#pragma unroll
      for (int r = 0; r < 4; r++)
        outp[obase[r] + t * 16] = KRATIO * (__expf(acc8[t][r] + c[r]) + KEPS);
    }
  }
}

// ---- k3b: reduce 8 partials -> v2x, v2sum  (grid EXACTLY 4160, guarded)
__global__ void k3b_reduce(const float* __restrict__ part, const float* __restrict__ vsumpart,
                           float* __restrict__ v2x, float* __restrict__ vsum) {
  const int i = blockIdx.x * 256 + threadIdx.x;
  if (i < 1048576) {
    const int bh = i >> 13, r = i & 8191;
    float s = 0.f;
#pragma unroll
    for (int c = 0; c < 8; c++) s += part[(size_t)(bh * 8 + c) * 8192 + r];
    v2x[i] = s;
  } else if (i < 1048576 + 16384) {
    const int k = i - 1048576, bh = k >> 7, j = k & 127;
    float s = 0.f;
#pragma unroll
    for (int c = 0; c < 8; c++) s += vsumpart[(size_t)(bh * 8 + c) * 128 + j];
    vsum[k] = s;
  }
}

// ---- k4m: out0 = (v1p @ v2x) / (v1p . vsum) via MFMA (r10, verified)
__global__ __launch_bounds__(256) void k4m(
    const float* __restrict__ v1p, const float* __restrict__ v2xg,
    const float* __restrict__ vsumg, float* __restrict__ out0) {
  const int l = threadIdx.x & 63, dt = threadIdx.x >> 6;  // wave = d-tile
  const int lm = l & 15, lk = l >> 4;
  const int bh = blockIdx.x >> 4, ch = blockIdx.x & 15;
  const int b = bh >> 3, h = bh & 7;
  bf16x8 Bh[4], Bl[4];
#pragma unroll
  for (int kc = 0; kc < 4; kc++) {
    float bfv[8];
#pragma unroll
    for (int e = 0; e < 8; e++)
      bfv[e] = v2xg[(size_t)bh * 8192 + (size_t)(kc * 32 + lk * 8 + e) * 64 + dt * 16 + lm];
    split8a(bfv, Bh[kc], Bl[kc]);
  }
  float vsr[4][8];
#pragma unroll
  for (int kc = 0; kc < 4; kc++)
#pragma unroll
    for (int e = 0; e < 8; e++)
      vsr[kc][e] = vsumg[bh * 128 + kc * 32 + lk * 8 + e];
  for (int s = 0; s < 16; s++) {
    const int nb = ch * 256 + s * 16;
    const float* pa = v1p + (size_t)((b * CN + nb + lm) * CHH + h) * CM;
    bf16x8 Ah[4], Al[4];
    float o2p = 0.f;
#pragma unroll
    for (int kc = 0; kc < 4; kc++) {
      float4 u = *(const float4*)(pa + kc * 32 + lk * 8);
      float4 v = *(const float4*)(pa + kc * 32 + lk * 8 + 4);
      split8(u, v, Ah[kc], Al[kc]);
      o2p += u.x * vsr[kc][0] + u.y * vsr[kc][1] + u.z * vsr[kc][2] + u.w * vsr[kc][3]
           + v.x * vsr[kc][4] + v.y * vsr[kc][5] + v.z * vsr[kc][6] + v.w * vsr[kc][7];
    }
    o2p += __shfl_xor(o2p, 16);
    o2p += __shfl_xor(o2p, 32);          // lane l: o2 of row (l&15)
    f32x4 acc = {0.f, 0.f, 0.f, 0.f};
#pragma unroll
    for (int kc = 0; kc < 4; kc++) {
      acc = MFMA_B16(Ah[kc], Bh[kc], acc);
      acc = MFMA_B16(Al[kc], Bh[kc], acc);
      acc = MFMA_B16(Ah[kc], Bl[kc], acc);
    }
#pragma unroll
    for (int r = 0; r < 4; r++) {
      const float inv = 1.0f / __shfl(o2p, lk * 4 + r);
      out0[(size_t)((b * CN + nb + lk * 4 + r) * CHH + h) * CD + dt * 16 + lm] = acc[r] * inv;
    }
  }
}

extern "C" void kernel_launch(void* const* d_in, const int* in_sizes, int n_in,
                              void* d_out, int out_size, void* d_ws, size_t ws_size,
                              hipStream_t stream) {
  (void)in_sizes; (void)n_in; (void)out_size; (void)ws_size;
  const float* x    = (const float*)d_in[0];
  const float* nv1  = (const float*)d_in[1];
  const float* nv2  = (const float*)d_in[2];
  const float* proj = (const float*)d_in[3];
  float* out  = (float*)d_out;
  float* out0 = out;
  float* v1p  = out + V1P_OFF;
  float* v2p  = out + V2P_OFF;

  // Scratch in the v1p output region (consumed by k3b BEFORE kv1e writes v1p):
  float* part     = v1p;                  // 1024*8192 = 8,388,608 floats
  float* vsumpart = v1p + 8388608;        // 1024*128 = 131,072 floats
  // Persistent scratch in ws (~4.3 MB):
  float* ws      = (float*)d_ws;
  float* wmax    = ws;                    // 128
  float* vsum    = ws + 128;              // 16,384
  float* v2x     = ws + 16512;            // 1,048,576
  float* partmax = ws + 16512 + 1048576;  // 1,024

  kp_stat   <<<dim3(1024), dim3(256), 0, stream>>>(nv2, proj, partmax);
  k2b_max   <<<dim3(1),    dim3(128), 0, stream>>>(partmax, wmax);
  kemit3    <<<dim3(1024), dim3(256), 0, stream>>>(nv2, x, proj, wmax, v2p, part, vsumpart);
  k3b_reduce<<<dim3(4160), dim3(256), 0, stream>>>(part, vsumpart, v2x, vsum);
  kv1e      <<<dim3(1024), dim3(256), 0, stream>>>(nv1, proj, v1p);
  k4m       <<<dim3(2048), dim3(256), 0, stream>>>(v1p, v2x, vsum, out0);
}

// Round 14
// 504.028 us; speedup vs baseline: 1.1300x; 1.1300x over previous
//
#include <hip/hip_runtime.h>
#include <math.h>

constexpr int CN = 4096, CHH = 8, CD = 64, CM = 128;
constexpr int V1P_OFF = 16 * 4096 * 8 * 64;             // 33554432 floats
constexpr int V2P_OFF = V1P_OFF + 16 * 4096 * 8 * 128;  // 100663296 floats
constexpr float KSCALE = 0.35355339059327373f;          // 64^-0.25 (tau=1)
constexpr float KRATIO = 0.08838834764831843f;          // 1/sqrt(128)
constexpr float KEPS   = 1e-6f;

typedef __attribute__((ext_vector_type(8))) short bf16x8;
typedef __attribute__((ext_vector_type(4))) float f32x4;

__device__ __forceinline__ float dot4(float4 a, float4 b) {
  return fmaf(a.x, b.x, fmaf(a.y, b.y, fmaf(a.z, b.z, a.w * b.w)));
}
__device__ __forceinline__ float4 scl4(float4 a, float s) {
  return make_float4(a.x * s, a.y * s, a.z * s, a.w * s);
}
__device__ __forceinline__ short bhi(float f) {
  return (short)(__float_as_uint(f) >> 16);          // truncate to bf16
}
__device__ __forceinline__ float bf2f(short s) {
  return __uint_as_float(((unsigned)(unsigned short)s) << 16);
}
__device__ __forceinline__ void split8(float4 u, float4 v, bf16x8& hi, bf16x8& lo) {
  float a[8] = {u.x, u.y, u.z, u.w, v.x, v.y, v.z, v.w};
#pragma unroll
  for (int e = 0; e < 8; e++) {
    short h = bhi(a[e]);
    hi[e] = h;
    lo[e] = bhi(a[e] - bf2f(h));
  }
}
__device__ __forceinline__ void split8a(const float* a, bf16x8& hi, bf16x8& lo) {
#pragma unroll
  for (int e = 0; e < 8; e++) {
    short h = bhi(a[e]);
    hi[e] = h;
    lo[e] = bhi(a[e] - bf2f(h));
  }
}

#define MFMA_B16(A, B, C) __builtin_amdgcn_mfma_f32_16x16x32_bf16(A, B, C, 0, 0, 0)

// full-precision proj fragments (hi+lo), ~128 VGPR
#define LOAD_BFRAGS(proj, lm, ko)                                   \
  bf16x8 Bh0[8], Bl0[8], Bh1[8], Bl1[8];                            \
  _Pragma("unroll")                                                 \
  for (int t = 0; t < 8; t++) {                                     \
    const float* pb = (proj) + (t * 16 + (lm)) * 64 + (ko);         \
    float4 p0 = *(const float4*)(pb);                               \
    float4 p1 = *(const float4*)(pb + 4);                           \
    float4 p2 = *(const float4*)(pb + 32);                          \
    float4 p3 = *(const float4*)(pb + 36);                          \
    split8(p0, p1, Bh0[t], Bl0[t]);                                 \
    split8(p2, p3, Bh1[t], Bl1[t]);                                 \
  }

// 6-term hi/lo MFMA chain for one j-tile t
#define PROJ_MFMA(acc, t)                                           \
  do {                                                              \
    acc = MFMA_B16(Ah0, Bh0[t], acc);                               \
    acc = MFMA_B16(Ah1, Bh1[t], acc);                               \
    acc = MFMA_B16(Al0, Bh0[t], acc);                               \
    acc = MFMA_B16(Al1, Bh1[t], acc);                               \
    acc = MFMA_B16(Ah0, Bl0[t], acc);                               \
    acc = MFMA_B16(Ah1, Bl1[t], acc);                               \
  } while (0)

// ---- kp_stat: per-(b,h)-chunk max of dd for v2. FULL 6-term precision
//      (r12: hi-only max fails — +eps breaks exp(-delta) cancellation).
__global__ __launch_bounds__(256) void kp_stat(
    const float* __restrict__ inp, const float* __restrict__ proj,
    float* __restrict__ outmax) {
  const int l = threadIdx.x & 63, w = threadIdx.x >> 6;
  const int lm = l & 15, lk = l >> 4, ko = lk * 8;
  LOAD_BFRAGS(proj, lm, ko);
  const int bh = blockIdx.x >> 3, ch = blockIdx.x & 7;
  const int b = bh >> 3, h = bh & 7;
  float bmax = -1e30f;
  for (int s = 0; s < 8; s++) {
    const int nb = ch * 512 + w * 128 + s * 16;
    const size_t rA = (size_t)((b * CN + nb + lm) * CHH + h);
    const float* pa = inp + rA * 64 + ko;
    float4 a0 = scl4(*(const float4*)(pa), KSCALE);
    float4 a1 = scl4(*(const float4*)(pa + 4), KSCALE);
    float4 a2 = scl4(*(const float4*)(pa + 32), KSCALE);
    float4 a3 = scl4(*(const float4*)(pa + 36), KSCALE);
    bf16x8 Ah0, Al0, Ah1, Al1;
    split8(a0, a1, Ah0, Al0);
    split8(a2, a3, Ah1, Al1);
    float rm[4] = {-1e30f, -1e30f, -1e30f, -1e30f};
#pragma unroll
    for (int t = 0; t < 8; t++) {
      f32x4 acc = {0.f, 0.f, 0.f, 0.f};
      PROJ_MFMA(acc, t);
#pragma unroll
      for (int r = 0; r < 4; r++) rm[r] = fmaxf(rm[r], acc[r]);
    }
    bmax = fmaxf(fmaxf(bmax, fmaxf(rm[0], rm[1])), fmaxf(rm[2], rm[3]));
  }
  float v = bmax;
#pragma unroll
  for (int d = 1; d < 64; d <<= 1) v = fmaxf(v, __shfl_xor(v, d));
  __shared__ float wred[4];
  if (l == 0) wred[w] = v;
  __syncthreads();
  if (threadIdx.x == 0)
    outmax[blockIdx.x] = fmaxf(fmaxf(wred[0], wred[1]), fmaxf(wred[2], wred[3]));
}

// ---- kp_emit: v2p = ratio*(exp(dd - 0.5*diag - wmax) + eps). wmax
//      reduced INLINE from the 8 chunk maxes (k2b launch folded away:
//      a 1-block kernel costs a whole-GPU serialization bubble).
__global__ __launch_bounds__(256) void kp_emit(
    const float* __restrict__ inp, const float* __restrict__ proj,
    const float* __restrict__ partmax, float* __restrict__ outp) {
  const int l = threadIdx.x & 63, w = threadIdx.x >> 6;
  const int lm = l & 15, lk = l >> 4, ko = lk * 8;
  LOAD_BFRAGS(proj, lm, ko);
  const int bh = blockIdx.x >> 3, ch = blockIdx.x & 7;
  const int b = bh >> 3, h = bh & 7;
  float whm = -1e30f;
#pragma unroll
  for (int c = 0; c < 8; c++) whm = fmaxf(whm, partmax[bh * 8 + c]);
  for (int s = 0; s < 8; s++) {
    const int nb = ch * 512 + w * 128 + s * 16;
    const size_t rA = (size_t)((b * CN + nb + lm) * CHH + h);
    const float* pa = inp + rA * 64 + ko;
    float4 a0 = scl4(*(const float4*)(pa), KSCALE);
    float4 a1 = scl4(*(const float4*)(pa + 4), KSCALE);
    float4 a2 = scl4(*(const float4*)(pa + 32), KSCALE);
    float4 a3 = scl4(*(const float4*)(pa + 36), KSCALE);
    bf16x8 Ah0, Al0, Ah1, Al1;
    split8(a0, a1, Ah0, Al0);
    split8(a2, a3, Ah1, Al1);
    float dp = dot4(a0, a0) + dot4(a1, a1) + dot4(a2, a2) + dot4(a3, a3);
    dp += __shfl_xor(dp, 16);
    dp += __shfl_xor(dp, 32);
    float c[4];
    size_t obase[4];
#pragma unroll
    for (int r = 0; r < 4; r++) {
      const float dg = __shfl(dp, lk * 4 + r);
      const size_t rr = (size_t)((b * CN + nb + lk * 4 + r) * CHH + h);
      c[r] = -(0.5f * dg + whm);
      obase[r] = rr * CM + lm;
    }
#pragma unroll
    for (int t = 0; t < 8; t++) {
      f32x4 acc = {0.f, 0.f, 0.f, 0.f};
      PROJ_MFMA(acc, t);
#pragma unroll
      for (int r = 0; r < 4; r++)
        outp[obase[r] + t * 16] = KRATIO * (__expf(acc[r] + c[r]) + KEPS);
    }
  }
}

// ---- k3m: partial v2x = v2p^T @ x via MFMA. 8 chunks/bh, 16 k-tiles each
//      (r11, verified: standalone — no barriers, loads pipeline across
//      iterations; r13 showed fusing this behind barriers loses 60us).
__global__ __launch_bounds__(256) void k3m(
    const float* __restrict__ v2p, const float* __restrict__ x,
    float* __restrict__ part, float* __restrict__ vsumpart) {
  const int l = threadIdx.x & 63, w = threadIdx.x >> 6;
  const int lm = l & 15, lk = l >> 4;
  const int bh = blockIdx.x >> 3, ch = blockIdx.x & 7;
  const int b = bh >> 3, h = bh & 7;
  const int jt0 = w * 2;
  f32x4 acc[2][4];
#pragma unroll
  for (int jj = 0; jj < 2; jj++)
#pragma unroll
    for (int dt = 0; dt < 4; dt++) acc[jj][dt] = (f32x4){0.f, 0.f, 0.f, 0.f};
  float vs0 = 0.f, vs1 = 0.f;
  for (int t = 0; t < 16; t++) {
    const int n0 = ch * 512 + t * 32 + lk * 8;       // this lane's k-row base
    bf16x8 Ah[2], Al[2];
#pragma unroll
    for (int jj = 0; jj < 2; jj++) {
      float af[8];
#pragma unroll
      for (int e = 0; e < 8; e++)
        af[e] = v2p[(size_t)((b * CN + n0 + e) * CHH + h) * CM + (jt0 + jj) * 16 + lm];
      split8a(af, Ah[jj], Al[jj]);
      float p = 0.f;
#pragma unroll
      for (int e = 0; e < 8; e++) p += af[e];
      if (jj == 0) vs0 += p; else vs1 += p;
    }
#pragma unroll
    for (int dt = 0; dt < 4; dt++) {
      float bfv[8];
#pragma unroll
      for (int e = 0; e < 8; e++)
        bfv[e] = x[(size_t)((b * CN + n0 + e) * CHH + h) * CD + dt * 16 + lm];
      bf16x8 Bh, Bl;
      split8a(bfv, Bh, Bl);
#pragma unroll
      for (int jj = 0; jj < 2; jj++) {
        acc[jj][dt] = MFMA_B16(Ah[jj], Bh, acc[jj][dt]);
        acc[jj][dt] = MFMA_B16(Al[jj], Bh, acc[jj][dt]);
        acc[jj][dt] = MFMA_B16(Ah[jj], Bl, acc[jj][dt]);
      }
    }
  }
  const size_t pbase = (size_t)blockIdx.x * 8192;     // = (bh*8+ch)*8192
#pragma unroll
  for (int jj = 0; jj < 2; jj++)
#pragma unroll
    for (int dt = 0; dt < 4; dt++)
#pragma unroll
      for (int r = 0; r < 4; r++)
        part[pbase + ((size_t)(jt0 + jj) * 16 + lk * 4 + r) * 64 + dt * 16 + lm] = acc[jj][dt][r];
  float v0 = vs0, v1 = vs1;
  v0 += __shfl_xor(v0, 16); v0 += __shfl_xor(v0, 32);
  v1 += __shfl_xor(v1, 16); v1 += __shfl_xor(v1, 32);
  if (lk == 0) {
    vsumpart[(size_t)blockIdx.x * 128 + (jt0 + 0) * 16 + lm] = v0;
    vsumpart[(size_t)blockIdx.x * 128 + (jt0 + 1) * 16 + lm] = v1;
  }
}

// ---- k3b: reduce 8 partials -> v2x, v2sum  (grid EXACTLY 4160, guarded)
__global__ void k3b_reduce(const float* __restrict__ part, const float* __restrict__ vsumpart,
                           float* __restrict__ v2x, float* __restrict__ vsum) {
  const int i = blockIdx.x * 256 + threadIdx.x;
  if (i < 1048576) {
    const int bh = i >> 13, r = i & 8191;
    float s = 0.f;
#pragma unroll
    for (int c = 0; c < 8; c++) s += part[(size_t)(bh * 8 + c) * 8192 + r];
    v2x[i] = s;
  } else if (i < 1048576 + 16384) {
    const int k = i - 1048576, bh = k >> 7, j = k & 127;
    float s = 0.f;
#pragma unroll
    for (int c = 0; c < 8; c++) s += vsumpart[(size_t)(bh * 8 + c) * 128 + j];
    vsum[k] = s;
  }
}

// ---- kv1e: fused v1p pass (r11, verified)
__global__ __launch_bounds__(256) void kv1e(
    const float* __restrict__ inp, const float* __restrict__ proj,
    float* __restrict__ outp) {
  const int l = threadIdx.x & 63, w = threadIdx.x >> 6;
  const int lm = l & 15, lk = l >> 4, ko = lk * 8;
  LOAD_BFRAGS(proj, lm, ko);
  const int bh = blockIdx.x >> 3, ch = blockIdx.x & 7;
  const int b = bh >> 3, h = bh & 7;
  for (int s = 0; s < 8; s++) {
    const int nb = ch * 512 + w * 128 + s * 16;
    const size_t rA = (size_t)((b * CN + nb + lm) * CHH + h);
    const float* pa = inp + rA * 64 + ko;
    float4 a0 = scl4(*(const float4*)(pa), KSCALE);
    float4 a1 = scl4(*(const float4*)(pa + 4), KSCALE);
    float4 a2 = scl4(*(const float4*)(pa + 32), KSCALE);
    float4 a3 = scl4(*(const float4*)(pa + 36), KSCALE);
    bf16x8 Ah0, Al0, Ah1, Al1;
    split8(a0, a1, Ah0, Al0);
    split8(a2, a3, Ah1, Al1);
    float dp = dot4(a0, a0) + dot4(a1, a1) + dot4(a2, a2) + dot4(a3, a3);
    dp += __shfl_xor(dp, 16);
    dp += __shfl_xor(dp, 32);
    f32x4 acc8[8];
#pragma unroll
    for (int t = 0; t < 8; t++) {
      f32x4 acc = {0.f, 0.f, 0.f, 0.f};
      PROJ_MFMA(acc, t);
      acc8[t] = acc;
    }
    float rm[4];
#pragma unroll
    for (int r = 0; r < 4; r++) {
      float m = acc8[0][r];
#pragma unroll
      for (int t = 1; t < 8; t++) m = fmaxf(m, acc8[t][r]);
      m = fmaxf(m, __shfl_xor(m, 1));
      m = fmaxf(m, __shfl_xor(m, 2));
      m = fmaxf(m, __shfl_xor(m, 4));
      m = fmaxf(m, __shfl_xor(m, 8));
      rm[r] = m;
    }
    float c[4];
    size_t obase[4];
#pragma unroll
    for (int r = 0; r < 4; r++) {
      const float dg = __shfl(dp, lk * 4 + r);
      const size_t rr = (size_t)((b * CN + nb + lk * 4 + r) * CHH + h);
      c[r] = -(0.5f * dg + rm[r]);
      obase[r] = rr * CM + lm;
    }
#pragma unroll
    for (int t = 0; t < 8; t++) {
#pragma unroll
      for (int r = 0; r < 4; r++)
        outp[obase[r] + t * 16] = KRATIO * (__expf(acc8[t][r] + c[r]) + KEPS);
    }
  }
}

// ---- k4m: out0 = (v1p @ v2x) / (v1p . vsum) via MFMA (r10, verified)
__global__ __launch_bounds__(256) void k4m(
    const float* __restrict__ v1p, const float* __restrict__ v2xg,
    const float* __restrict__ vsumg, float* __restrict__ out0) {
  const int l = threadIdx.x & 63, dt = threadIdx.x >> 6;  // wave = d-tile
  const int lm = l & 15, lk = l >> 4;
  const int bh = blockIdx.x >> 4, ch = blockIdx.x & 15;
  const int b = bh >> 3, h = bh & 7;
  bf16x8 Bh[4], Bl[4];
#pragma unroll
  for (int kc = 0; kc < 4; kc++) {
    float bfv[8];
#pragma unroll
    for (int e = 0; e < 8; e++)
      bfv[e] = v2xg[(size_t)bh * 8192 + (size_t)(kc * 32 + lk * 8 + e) * 64 + dt * 16 + lm];
    split8a(bfv, Bh[kc], Bl[kc]);
  }
  float vsr[4][8];
#pragma unroll
  for (int kc = 0; kc < 4; kc++)
#pragma unroll
    for (int e = 0; e < 8; e++)
      vsr[kc][e] = vsumg[bh * 128 + kc * 32 + lk * 8 + e];
  for (int s = 0; s < 16; s++) {
    const int nb = ch * 256 + s * 16;
    const float* pa = v1p + (size_t)((b * CN + nb + lm) * CHH + h) * CM;
    bf16x8 Ah[4], Al[4];
    float o2p = 0.f;
#pragma unroll
    for (int kc = 0; kc < 4; kc++) {
      float4 u = *(const float4*)(pa + kc * 32 + lk * 8);
      float4 v = *(const float4*)(pa + kc * 32 + lk * 8 + 4);
      split8(u, v, Ah[kc], Al[kc]);
      o2p += u.x * vsr[kc][0] + u.y * vsr[kc][1] + u.z * vsr[kc][2] + u.w * vsr[kc][3]
           + v.x * vsr[kc][4] + v.y * vsr[kc][5] + v.z * vsr[kc][6] + v.w * vsr[kc][7];
    }
    o2p += __shfl_xor(o2p, 16);
    o2p += __shfl_xor(o2p, 32);          // lane l: o2 of row (l&15)
    f32x4 acc = {0.f, 0.f, 0.f, 0.f};
#pragma unroll
    for (int kc = 0; kc < 4; kc++) {
      acc = MFMA_B16(Ah[kc], Bh[kc], acc);
      acc = MFMA_B16(Al[kc], Bh[kc], acc);
      acc = MFMA_B16(Ah[kc], Bl[kc], acc);
    }
#pragma unroll
    for (int r = 0; r < 4; r++) {
      const float inv = 1.0f / __shfl(o2p, lk * 4 + r);
      out0[(size_t)((b * CN + nb + lk * 4 + r) * CHH + h) * CD + dt * 16 + lm] = acc[r] * inv;
    }
  }
}

extern "C" void kernel_launch(void* const* d_in, const int* in_sizes, int n_in,
                              void* d_out, int out_size, void* d_ws, size_t ws_size,
                              hipStream_t stream) {
  (void)in_sizes; (void)n_in; (void)out_size; (void)ws_size;
  const float* x    = (const float*)d_in[0];
  const float* nv1  = (const float*)d_in[1];
  const float* nv2  = (const float*)d_in[2];
  const float* proj = (const float*)d_in[3];
  float* out  = (float*)d_out;
  float* out0 = out;
  float* v1p  = out + V1P_OFF;
  float* v2p  = out + V2P_OFF;

  // Scratch in the v1p output region (consumed by k3b BEFORE kv1e writes v1p):
  float* part     = v1p;                  // 1024*8192 = 8,388,608 floats
  float* vsumpart = v1p + 8388608;        // 1024*128 = 131,072 floats
  // Persistent scratch in ws (~4.3 MB):
  float* ws      = (float*)d_ws;
  float* vsum    = ws;                    // 16,384
  float* v2x     = ws + 16384;            // 1,048,576
  float* partmax = ws + 16384 + 1048576;  // 1,024

  kp_stat   <<<dim3(1024), dim3(256), 0, stream>>>(nv2, proj, partmax);
  kp_emit   <<<dim3(1024), dim3(256), 0, stream>>>(nv2, proj, partmax, v2p);
  k3m       <<<dim3(1024), dim3(256), 0, stream>>>(v2p, x, part, vsumpart);
  k3b_reduce<<<dim3(4160), dim3(256), 0, stream>>>(part, vsumpart, v2x, vsum);
  kv1e      <<<dim3(1024), dim3(256), 0, stream>>>(nv1, proj, v1p);
  k4m       <<<dim3(2048), dim3(256), 0, stream>>>(v1p, v2x, vsum, out0);
}